// Round 1
// baseline (126.823 us; speedup 1.0000x reference)
//
#include <hip/hip_runtime.h>

// BahdanauAttention: B=4, LQ=512, LK=512, H=256, all f32.
//   q = query@Wq^T+bq ; k = values@Wk^T+bk
//   scores = sum_h We[h]*tanh(q+k) + be  -> softmax over k -> context = attn@values
// Algebra: tanh(x)=1-2/(exp(2x)+1); be and sum(We) are additive constants on
// scores -> softmax-invariant -> dropped. We store qc=(q)*2log2e, kc=(k)*2log2e
// so inner loop is: add, exp2, add, rcp, fma  (3 VALU + 2 trans per element).
// softmax computes softmax(-2t) via exponent (min(t)-t)*2log2e.

#define SCALE2 2.8853900817779268f   // 2*log2(e)

#if defined(__has_builtin)
#if __has_builtin(__builtin_amdgcn_exp2f)
#define FEXP2(x) __builtin_amdgcn_exp2f(x)
#endif
#if __has_builtin(__builtin_amdgcn_rcpf)
#define FRCP(x) __builtin_amdgcn_rcpf(x)
#endif
#endif
#ifndef FEXP2
#define FEXP2(x) exp2f(x)
#endif
#ifndef FRCP
#define FRCP(x) (1.0f/(x))
#endif

// Y[n][o] = (sum_h X[n][h]*W[o][h] + bias[o]) * SCALE2 ; X:(2048,256) W:(256,256)
__global__ __launch_bounds__(256) void proj_kernel(
    const float* __restrict__ X, const float* __restrict__ W,
    const float* __restrict__ bias, float* __restrict__ Y)
{
  const int n0 = blockIdx.x * 64;
  const int o0 = blockIdx.y * 64;
  const int t  = threadIdx.x;
  const int tx = t & 15, ty = t >> 4;
  __shared__ float Xs[64][33];
  __shared__ float Ws[64][33];
  float acc[4][4] = {};
  for (int h0 = 0; h0 < 256; h0 += 32) {
    __syncthreads();
#pragma unroll
    for (int rep = 0; rep < 2; ++rep) {
      int idx = rep * 256 + t;              // 0..511
      int r = idx >> 3, c = (idx & 7) << 2; // 64 rows x 32 cols
      float4 xv = *(const float4*)(X + (size_t)(n0 + r) * 256 + h0 + c);
      Xs[r][c] = xv.x; Xs[r][c+1] = xv.y; Xs[r][c+2] = xv.z; Xs[r][c+3] = xv.w;
      float4 wv = *(const float4*)(W + (size_t)(o0 + r) * 256 + h0 + c);
      Ws[r][c] = wv.x; Ws[r][c+1] = wv.y; Ws[r][c+2] = wv.z; Ws[r][c+3] = wv.w;
    }
    __syncthreads();
#pragma unroll
    for (int hh = 0; hh < 32; ++hh) {
      float a[4], bb[4];
#pragma unroll
      for (int i = 0; i < 4; ++i) a[i]  = Xs[ty*4+i][hh];
#pragma unroll
      for (int j = 0; j < 4; ++j) bb[j] = Ws[tx*4+j][hh];
#pragma unroll
      for (int i = 0; i < 4; ++i)
#pragma unroll
        for (int j = 0; j < 4; ++j)
          acc[i][j] = fmaf(a[i], bb[j], acc[i][j]);
    }
  }
  const float4 bv = *(const float4*)(bias + o0 + tx*4);
#pragma unroll
  for (int i = 0; i < 4; ++i) {
    int n = n0 + ty*4 + i;
    float4 st;
    st.x = (acc[i][0] + bv.x) * SCALE2;
    st.y = (acc[i][1] + bv.y) * SCALE2;
    st.z = (acc[i][2] + bv.z) * SCALE2;
    st.w = (acc[i][3] + bv.w) * SCALE2;
    *(float4*)(Y + (size_t)n * 256 + o0 + tx*4) = st;
  }
}

// sout[b][q][k] = sum_h We[h] * rcp(exp2(qc+kc)+1)   (this is t; scores = C-2t)
__global__ __launch_bounds__(256) void scores_kernel(
    const float* __restrict__ qc, const float* __restrict__ kc,
    const float* __restrict__ We, float* __restrict__ sout)
{
  const int kt = blockIdx.x;   // 0..7   k-tile of 64
  const int qt = blockIdx.y;   // 0..31  q-tile of 16
  const int b  = blockIdx.z;   // 0..3
  const int t  = threadIdx.x;
  const int qi = t >> 4;           // 0..15 : one q-row per thread
  const int k4 = (t & 15) << 2;    // 0..60 : 4 k-cols per thread

  __shared__ float ksT[64][64];    // [hh][ki] transposed k-chunk
  __shared__ float qs[16][65];     // padded to spread banks

  const float* qbase = qc + (size_t)(b*512 + qt*16) * 256;
  const float* kbase = kc + (size_t)(b*512 + kt*64) * 256;

  float acc0 = 0.f, acc1 = 0.f, acc2 = 0.f, acc3 = 0.f;

  for (int h0 = 0; h0 < 256; h0 += 64) {
    __syncthreads();
    {   // stage q tile 16x64 (one float4 per thread)
      int r = t >> 4, c = (t & 15) << 2;
      float4 v = *(const float4*)(qbase + (size_t)r*256 + h0 + c);
      qs[r][c] = v.x; qs[r][c+1] = v.y; qs[r][c+2] = v.z; qs[r][c+3] = v.w;
    }
#pragma unroll
    for (int rep = 0; rep < 4; ++rep) {  // stage k tile 64x64 transposed
      int idx = rep*256 + t;
      int r = idx >> 4, c = (idx & 15) << 2;
      float4 v = *(const float4*)(kbase + (size_t)r*256 + h0 + c);
      ksT[c  ][r] = v.x; ksT[c+1][r] = v.y; ksT[c+2][r] = v.z; ksT[c+3][r] = v.w;
    }
    __syncthreads();
#pragma unroll 8
    for (int hh = 0; hh < 64; ++hh) {
      float w  = We[h0 + hh];                       // uniform -> s_load
      float qv = qs[qi][hh];                        // broadcast
      float4 kv = *(const float4*)&ksT[hh][k4];     // conflict-free b128
      float x0 = qv + kv.x, x1 = qv + kv.y, x2 = qv + kv.z, x3 = qv + kv.w;
      float r0 = FRCP(FEXP2(x0) + 1.f);
      float r1 = FRCP(FEXP2(x1) + 1.f);
      float r2 = FRCP(FEXP2(x2) + 1.f);
      float r3 = FRCP(FEXP2(x3) + 1.f);
      acc0 = fmaf(w, r0, acc0);
      acc1 = fmaf(w, r1, acc1);
      acc2 = fmaf(w, r2, acc2);
      acc3 = fmaf(w, r3, acc3);
    }
  }
  float4 st = {acc0, acc1, acc2, acc3};
  *(float4*)(sout + (size_t)(b*512 + qt*16 + qi)*512 + kt*64 + k4) = st;
}

// in-place: attn_row = softmax(-2*t_row). exponent (mn - t)*SCALE2, mn = min(t).
__global__ __launch_bounds__(256) void softmax_kernel(float* __restrict__ attn)
{
  const int t    = threadIdx.x;
  const int lane = t & 63;
  const int row  = blockIdx.x * 4 + (t >> 6);
  float* p = attn + (size_t)row * 512;
  float v[8];
  float mn = 1e30f;
#pragma unroll
  for (int i = 0; i < 8; ++i) { v[i] = p[i*64 + lane]; mn = fminf(mn, v[i]); }
#pragma unroll
  for (int off = 32; off > 0; off >>= 1) mn = fminf(mn, __shfl_xor(mn, off, 64));
  float sum = 0.f;
#pragma unroll
  for (int i = 0; i < 8; ++i) { v[i] = FEXP2((mn - v[i]) * SCALE2); sum += v[i]; }
#pragma unroll
  for (int off = 32; off > 0; off >>= 1) sum += __shfl_xor(sum, off, 64);
  const float inv = 1.0f / sum;
#pragma unroll
  for (int i = 0; i < 8; ++i) p[i*64 + lane] = v[i] * inv;
}

// ctx[row][h] = sum_k attn[row][k] * values[b][k][h], 8 rows/block
__global__ __launch_bounds__(256) void context_kernel(
    const float* __restrict__ attn, const float* __restrict__ values,
    float* __restrict__ ctx)
{
  const int t    = threadIdx.x;
  const int row0 = blockIdx.x * 8;        // 0..2040
  const int b    = row0 >> 9;
  const int h4   = (t & 63) << 2;
  const int r0   = (t >> 6) * 2;          // wave-uniform
  __shared__ float attn_s[8][512];
  __shared__ float vs[32][256];
#pragma unroll
  for (int rep = 0; rep < 4; ++rep) {     // stage attn 8x512
    int idx = rep*256 + t;
    int r = idx >> 7, c = (idx & 127) << 2;
    *(float4*)&attn_s[r][c] = *(const float4*)(attn + (size_t)(row0 + r)*512 + c);
  }
  float4 acc0 = {0,0,0,0}, acc1 = {0,0,0,0};
  const float* vbase = values + (size_t)b * 512 * 256;
  for (int kc = 0; kc < 512; kc += 32) {
    __syncthreads();
#pragma unroll
    for (int rep = 0; rep < 8; ++rep) {   // stage values 32x256
      int idx = rep*256 + t;
      int r = idx >> 6, c = (idx & 63) << 2;
      *(float4*)&vs[r][c] = *(const float4*)(vbase + (size_t)(kc + r)*256 + c);
    }
    __syncthreads();
#pragma unroll 8
    for (int kk = 0; kk < 32; ++kk) {
      float4 v = *(const float4*)&vs[kk][h4];   // lanes consecutive
      float a0 = attn_s[r0  ][kc+kk];           // wave-uniform broadcast
      float a1 = attn_s[r0+1][kc+kk];
      acc0.x = fmaf(a0, v.x, acc0.x); acc0.y = fmaf(a0, v.y, acc0.y);
      acc0.z = fmaf(a0, v.z, acc0.z); acc0.w = fmaf(a0, v.w, acc0.w);
      acc1.x = fmaf(a1, v.x, acc1.x); acc1.y = fmaf(a1, v.y, acc1.y);
      acc1.z = fmaf(a1, v.z, acc1.z); acc1.w = fmaf(a1, v.w, acc1.w);
    }
  }
  *(float4*)(ctx + (size_t)(row0 + r0    )*256 + h4) = acc0;
  *(float4*)(ctx + (size_t)(row0 + r0 + 1)*256 + h4) = acc1;
}

extern "C" void kernel_launch(void* const* d_in, const int* in_sizes, int n_in,
                              void* d_out, int out_size, void* d_ws, size_t ws_size,
                              hipStream_t stream)
{
  const float* query  = (const float*)d_in[0];
  const float* values = (const float*)d_in[1];
  const float* Wq     = (const float*)d_in[2];
  const float* bq     = (const float*)d_in[3];
  const float* Wk     = (const float*)d_in[4];
  const float* bk     = (const float*)d_in[5];
  const float* We     = (const float*)d_in[6];
  // d_in[7] = be: additive constant on scores -> softmax-invariant -> unused.

  float* ctx  = (float*)d_out;                    // 4*512*256 = 524288 floats
  float* attn = ctx + 4*512*256;                  // 4*512*512 = 1048576 floats
  float* qc   = ctx;                              // reuse ctx region for qc (2MB);
                                                  // overwritten by context_kernel last
  float* kc   = (float*)d_ws;                     // 2MB workspace

  dim3 pgrid(32, 4);
  proj_kernel<<<pgrid, 256, 0, stream>>>(query,  Wq, bq, qc);
  proj_kernel<<<pgrid, 256, 0, stream>>>(values, Wk, bk, kc);
  dim3 sgrid(8, 32, 4);
  scores_kernel<<<sgrid, 256, 0, stream>>>(qc, kc, We, attn);
  softmax_kernel<<<512, 256, 0, stream>>>(attn);
  context_kernel<<<256, 256, 0, stream>>>(attn, values, ctx);
}

// Round 2
// 81.165 us; speedup vs baseline: 1.5625x; 1.5625x over previous
//
#include <hip/hip_runtime.h>

// BahdanauAttention: B=4, LQ=512, LK=512, H=256, all f32.
//   q = query@Wq^T+bq ; k = values@Wk^T+bk
//   scores = sum_h We[h]*tanh(q+k) + be -> softmax over k -> context = attn@values
//
// Algebra:
//   tanh(x) = 1 - 2/(exp(2x)+1); be and sum(We) are additive constants on scores
//   -> softmax-invariant -> dropped. With t = sum_h We*sigma, softmax(scores) =
//   softmax(-2t), computed as exp2((min-t)*2log2e).
//   exp(2(q+k)) = exp2(SCALE2*q) * exp2(SCALE2*k) = Eq*Ek, both PRECOMPUTED in the
//   projection epilogue. Scores inner loop: x=fma(Eq,Ek,1); r=rcp(x); acc=fma(w,r)
//   -> 2 VALU + 1 trans per element (was 3 VALU + 2 trans).
//   Ek is stored TRANSPOSED [b][h][k] by the proj kernel so the scores kernel
//   stages it with contiguous b128 LDS writes (zero bank conflict; the old
//   in-kernel transpose cost 8M conflict cycles).

#define SCALE2 2.8853900817779268f   // 2*log2(e)

#if defined(__has_builtin)
#if __has_builtin(__builtin_amdgcn_exp2f)
#define FEXP2(x) __builtin_amdgcn_exp2f(x)
#endif
#if __has_builtin(__builtin_amdgcn_rcpf)
#define FRCP(x) __builtin_amdgcn_rcpf(x)
#endif
#endif
#ifndef FEXP2
#define FEXP2(x) exp2f(x)
#endif
#ifndef FRCP
#define FRCP(x) (1.0f/(x))
#endif

// Fused projections. blockIdx.z = 0: Eq[n][o] = exp2(SCALE2*(query@Wq^T+bq))
//                    blockIdx.z = 1: EkT[b][o][k] = exp2(SCALE2*(values@Wk^T+bk))
// tile 64n x 64o, 512 threads (acc 2x4), K=256.
// LDS transposed+padded [32][68]: staging writes ~4-way, fragment reads b64/b128
// conflict-free (2-way max).
__global__ __launch_bounds__(512) void proj_kernel(
    const float* __restrict__ Q, const float* __restrict__ V,
    const float* __restrict__ Wq, const float* __restrict__ bq,
    const float* __restrict__ Wk, const float* __restrict__ bk,
    float* __restrict__ Eq, float* __restrict__ EkT)
{
  const int n0 = blockIdx.x * 64;
  const int o0 = blockIdx.y * 64;
  const bool isK = (blockIdx.z == 1);
  const float* X    = isK ? V  : Q;
  const float* W    = isK ? Wk : Wq;
  const float* bias = isK ? bk : bq;
  const int t  = threadIdx.x;
  const int tx = t & 15;        // o quad: o = o0 + tx*4 + j
  const int ty = t >> 4;        // 0..31 : n pair: n = n0 + ty*2 + i
  __shared__ float Xst[32][68]; // [h][n], stride 68 -> rows 16B aligned
  __shared__ float Wst[32][68]; // [h][o]
  float acc[2][4] = {};
  for (int h0 = 0; h0 < 256; h0 += 32) {
    __syncthreads();
    {
      int r = t >> 3, c = (t & 7) << 2;   // 64 rows x 32 cols, 1 float4 each
      float4 xv = *(const float4*)(X + (size_t)(n0 + r) * 256 + h0 + c);
      Xst[c  ][r] = xv.x; Xst[c+1][r] = xv.y; Xst[c+2][r] = xv.z; Xst[c+3][r] = xv.w;
      float4 wv = *(const float4*)(W + (size_t)(o0 + r) * 256 + h0 + c);
      Wst[c  ][r] = wv.x; Wst[c+1][r] = wv.y; Wst[c+2][r] = wv.z; Wst[c+3][r] = wv.w;
    }
    __syncthreads();
#pragma unroll 8
    for (int hh = 0; hh < 32; ++hh) {
      float2 a  = *(const float2*)&Xst[hh][ty*2];   // b64, 8B aligned
      float4 bb = *(const float4*)&Wst[hh][tx*4];   // b128, 16B aligned
      acc[0][0] = fmaf(a.x, bb.x, acc[0][0]); acc[0][1] = fmaf(a.x, bb.y, acc[0][1]);
      acc[0][2] = fmaf(a.x, bb.z, acc[0][2]); acc[0][3] = fmaf(a.x, bb.w, acc[0][3]);
      acc[1][0] = fmaf(a.y, bb.x, acc[1][0]); acc[1][1] = fmaf(a.y, bb.y, acc[1][1]);
      acc[1][2] = fmaf(a.y, bb.z, acc[1][2]); acc[1][3] = fmaf(a.y, bb.w, acc[1][3]);
    }
  }
  const float4 bv = *(const float4*)(bias + o0 + tx*4);
  float e[2][4];
#pragma unroll
  for (int i = 0; i < 2; ++i) {
    e[i][0] = FEXP2(SCALE2 * (acc[i][0] + bv.x));
    e[i][1] = FEXP2(SCALE2 * (acc[i][1] + bv.y));
    e[i][2] = FEXP2(SCALE2 * (acc[i][2] + bv.z));
    e[i][3] = FEXP2(SCALE2 * (acc[i][3] + bv.w));
  }
  if (!isK) {
#pragma unroll
    for (int i = 0; i < 2; ++i) {
      float4 st = {e[i][0], e[i][1], e[i][2], e[i][3]};
      *(float4*)(Eq + (size_t)(n0 + ty*2 + i) * 256 + o0 + tx*4) = st;
    }
  } else {
    const int b  = n0 >> 9;
    const int k0 = (n0 & 511) + ty*2;
#pragma unroll
    for (int j = 0; j < 4; ++j) {
      float2 st = {e[0][j], e[1][j]};
      *(float2*)(EkT + (size_t)b*131072 + (size_t)(o0 + tx*4 + j)*512 + k0) = st;
    }
  }
}

// traw[b][q][k] = sum_h We[h] * rcp(Eq*Ek + 1)   (scores = C - 2*traw)
// tile 8q x 64k, 256 threads, 2 el/thread. grid (8,64,4) = 2048 blocks.
__global__ __launch_bounds__(256) void scores_kernel(
    const float* __restrict__ Eq, const float* __restrict__ EkT,
    const float* __restrict__ We, float* __restrict__ sout)
{
  const int kt = blockIdx.x;      // 0..7
  const int qt = blockIdx.y;      // 0..63
  const int b  = blockIdx.z;      // 0..3
  const int t  = threadIdx.x;
  const int qi = t >> 5;          // 0..7
  const int k2 = (t & 31) << 1;   // 0..62

  __shared__ float ks[64][64];    // [h][k] — staged straight from EkT, no transpose
  __shared__ float qs[8][68];

  const float* eqbase = Eq  + (size_t)(b*512 + qt*8) * 256;
  const float* ekbase = EkT + (size_t)b*131072 + (size_t)kt*64;

  float acc0 = 0.f, acc1 = 0.f;

  for (int h0 = 0; h0 < 256; h0 += 64) {
    __syncthreads();
    if (t < 128) {                 // stage q tile 8x64
      int r = t >> 4, c = (t & 15) << 2;
      float4 v = *(const float4*)(eqbase + (size_t)r*256 + h0 + c);
      qs[r][c] = v.x; qs[r][c+1] = v.y; qs[r][c+2] = v.z; qs[r][c+3] = v.w;
    }
#pragma unroll
    for (int rep = 0; rep < 4; ++rep) {  // stage k tile 64h x 64k, b128 writes
      int idx = rep*256 + t;
      int r = idx >> 4, c = (idx & 15) << 2;
      *(float4*)&ks[r][c] = *(const float4*)(ekbase + (size_t)(h0 + r)*512 + c);
    }
    __syncthreads();
#pragma unroll 8
    for (int hh = 0; hh < 64; ++hh) {
      float w  = We[h0 + hh];                      // uniform -> s_load
      float qv = qs[qi][hh];                       // broadcast
      float2 kv = *(const float2*)&ks[hh][k2];     // b64, 2-way = free
      float x0 = fmaf(qv, kv.x, 1.0f);
      float x1 = fmaf(qv, kv.y, 1.0f);
      acc0 = fmaf(w, FRCP(x0), acc0);
      acc1 = fmaf(w, FRCP(x1), acc1);
    }
  }
  float2 st = {acc0, acc1};
  *(float2*)(sout + (size_t)(b*512 + qt*8 + qi)*512 + kt*64 + k2) = st;
}

// Fused softmax + context. 8 rows/block, 256 blocks.
// Reads raw t from attn buffer, writes normalized attn (softmax(-2t)) in place
// and ctx[row][h] = sum_k attn[row][k]*values[b][k][h].
__global__ __launch_bounds__(256) void ctx_kernel(
    const float* __restrict__ values, float* attn, float* __restrict__ ctx)
{
  const int t    = threadIdx.x;
  const int row0 = blockIdx.x * 8;
  const int b    = row0 >> 9;
  __shared__ float ts[8][512];
  __shared__ float vs[32][256];
#pragma unroll
  for (int rep = 0; rep < 4; ++rep) {     // stage raw scores 8x512
    int idx = rep*256 + t;
    int r = idx >> 7, c = (idx & 127) << 2;
    *(float4*)&ts[r][c] = *(const float4*)(attn + (size_t)(row0 + r)*512 + c);
  }
  __syncthreads();
  {  // softmax: 32 threads per row; exponent (mn - v)*SCALE2 since scores = C-2t
    const int row = t >> 5, j = t & 31;
    float v[16];
    float mn = 1e30f;
#pragma unroll
    for (int i = 0; i < 16; ++i) { v[i] = ts[row][j + 32*i]; mn = fminf(mn, v[i]); }
#pragma unroll
    for (int off = 16; off > 0; off >>= 1) mn = fminf(mn, __shfl_xor(mn, off, 32));
    float sum = 0.f;
#pragma unroll
    for (int i = 0; i < 16; ++i) { v[i] = FEXP2((mn - v[i]) * SCALE2); sum += v[i]; }
#pragma unroll
    for (int off = 16; off > 0; off >>= 1) sum += __shfl_xor(sum, off, 32);
    const float inv = 1.0f / sum;
    float* gp = attn + (size_t)(row0 + row)*512 + j;
#pragma unroll
    for (int i = 0; i < 16; ++i) {
      float p = v[i] * inv;
      ts[row][j + 32*i] = p;
      gp[32*i] = p;
    }
  }
  // context
  const int h4 = (t & 63) << 2;
  const int r0 = (t >> 6) * 2;            // wave-uniform
  float4 acc0 = {0,0,0,0}, acc1 = {0,0,0,0};
  const float* vbase = values + (size_t)b * 512 * 256;
  for (int kc = 0; kc < 512; kc += 32) {
    __syncthreads();
#pragma unroll
    for (int rep = 0; rep < 8; ++rep) {   // stage values 32x256
      int idx = rep*256 + t;
      int r = idx >> 6, c = (idx & 63) << 2;
      *(float4*)&vs[r][c] = *(const float4*)(vbase + (size_t)(kc + r)*256 + c);
    }
    __syncthreads();
#pragma unroll 8
    for (int kk = 0; kk < 32; ++kk) {
      float4 v = *(const float4*)&vs[kk][h4];   // lanes consecutive, conflict-free
      float a0 = ts[r0  ][kc+kk];               // wave-uniform broadcast
      float a1 = ts[r0+1][kc+kk];
      acc0.x = fmaf(a0, v.x, acc0.x); acc0.y = fmaf(a0, v.y, acc0.y);
      acc0.z = fmaf(a0, v.z, acc0.z); acc0.w = fmaf(a0, v.w, acc0.w);
      acc1.x = fmaf(a1, v.x, acc1.x); acc1.y = fmaf(a1, v.y, acc1.y);
      acc1.z = fmaf(a1, v.z, acc1.z); acc1.w = fmaf(a1, v.w, acc1.w);
    }
  }
  *(float4*)(ctx + (size_t)(row0 + r0    )*256 + h4) = acc0;
  *(float4*)(ctx + (size_t)(row0 + r0 + 1)*256 + h4) = acc1;
}

extern "C" void kernel_launch(void* const* d_in, const int* in_sizes, int n_in,
                              void* d_out, int out_size, void* d_ws, size_t ws_size,
                              hipStream_t stream)
{
  const float* query  = (const float*)d_in[0];
  const float* values = (const float*)d_in[1];
  const float* Wq     = (const float*)d_in[2];
  const float* bq     = (const float*)d_in[3];
  const float* Wk     = (const float*)d_in[4];
  const float* bk     = (const float*)d_in[5];
  const float* We     = (const float*)d_in[6];
  // d_in[7] = be: additive constant on scores -> softmax-invariant -> unused.

  float* ctx  = (float*)d_out;            // 4*512*256 = 524288 floats
  float* attn = ctx + 4*512*256;          // 4*512*512 floats
  float* Eq   = ctx;                      // alias ctx region (2MB); overwritten
                                          // by ctx_kernel after last Eq read
  float* EkT  = (float*)d_ws;             // 2MB workspace, layout [b][h][k]

  proj_kernel  <<<dim3(32, 4, 2), 512, 0, stream>>>(query, values, Wq, bq, Wk, bk, Eq, EkT);
  scores_kernel<<<dim3(8, 64, 4), 256, 0, stream>>>(Eq, EkT, We, attn);
  ctx_kernel   <<<256, 256, 0, stream>>>(values, attn, ctx);
}